// Round 1
// baseline (207.444 us; speedup 1.0000x reference)
//
#include <hip/hip_runtime.h>
#include <math.h>

// Problem: B=16, C=256, H=W=64, r=16.
// dct = (1/4096) * D @ X @ D^T per (b,c) slice, D[k,n] = cos(pi*k*(2n+1)/128)
// top1[b,c] = max(dct slice); h = relu(top1 @ w1); weights = sigmoid(h @ w2)
// out = ip * weights[b,c]

#define TSTRIDE 68  // padded stride for intermediate T to soften write conflicts

__global__ __launch_bounds__(256) void dct_max_kernel(const float* __restrict__ ip,
                                                      float* __restrict__ top1) {
    __shared__ float Xs[64 * 64];      // X[h][w]
    __shared__ float Dt[64 * 64];      // Dt[n][k] = cos(pi*k*(2n+1)/128) == D[k][n]
    __shared__ float T[64 * TSTRIDE];  // T[u][w] = sum_h D[u,h] X[h,w]
    __shared__ float red[4];

    const int t = threadIdx.x;
    const int bc = blockIdx.x;
    const float* src = ip + (size_t)bc * 4096;

    // Load X slice (coalesced float4)
    const float4* src4 = (const float4*)src;
    float4* Xs4 = (float4*)Xs;
#pragma unroll
    for (int i = 0; i < 4; ++i) Xs4[i * 256 + t] = src4[i * 256 + t];

    // Build cosine matrix: Dt[n*64+k] = cos(pi * ((k*(2n+1)) mod 256) / 128)
#pragma unroll
    for (int i = 0; i < 16; ++i) {
        int idx = i * 256 + t;
        int n = idx >> 6, k = idx & 63;
        int m = (k * (2 * n + 1)) & 255;
        Dt[idx] = cospif((float)m * (1.0f / 128.0f));
    }
    __syncthreads();

    const int tx = t & 15;   // -> w (stage A) / v (stage B), 4-wide
    const int ty = t >> 4;   // -> u, 4-wide
    const int a0 = 4 * tx;
    const int b0 = 4 * ty;

    // ---- Stage A: T[u][w] = sum_h Dt[h][u] * X[h][w] ----
    float acc[4][4];
#pragma unroll
    for (int i = 0; i < 4; ++i)
#pragma unroll
        for (int j = 0; j < 4; ++j) acc[i][j] = 0.0f;

    for (int h = 0; h < 64; ++h) {
        float4 xv = *(const float4*)&Xs[h * 64 + a0];  // X[h][w0..w0+3]
        float4 dv = *(const float4*)&Dt[h * 64 + b0];  // D[u0..u0+3][h]
        const float xs[4] = {xv.x, xv.y, xv.z, xv.w};
        const float ds[4] = {dv.x, dv.y, dv.z, dv.w};
#pragma unroll
        for (int i = 0; i < 4; ++i)
#pragma unroll
            for (int j = 0; j < 4; ++j) acc[i][j] = fmaf(ds[i], xs[j], acc[i][j]);
    }
#pragma unroll
    for (int i = 0; i < 4; ++i) {
        float4 v = make_float4(acc[i][0], acc[i][1], acc[i][2], acc[i][3]);
        *(float4*)&T[(b0 + i) * TSTRIDE + a0] = v;
    }
    __syncthreads();

    // ---- Stage B: Y[u][v] = sum_w T[u][w] * Dt[w][v]; fuse max ----
#pragma unroll
    for (int i = 0; i < 4; ++i)
#pragma unroll
        for (int j = 0; j < 4; ++j) acc[i][j] = 0.0f;

    for (int w = 0; w < 64; ++w) {
        float tv[4];
#pragma unroll
        for (int i = 0; i < 4; ++i) tv[i] = T[(b0 + i) * TSTRIDE + w];
        float4 dv = *(const float4*)&Dt[w * 64 + a0];  // D[v0..v0+3][w]
        const float ds[4] = {dv.x, dv.y, dv.z, dv.w};
#pragma unroll
        for (int i = 0; i < 4; ++i)
#pragma unroll
            for (int j = 0; j < 4; ++j) acc[i][j] = fmaf(tv[i], ds[j], acc[i][j]);
    }

    float m = acc[0][0];
#pragma unroll
    for (int i = 0; i < 4; ++i)
#pragma unroll
        for (int j = 0; j < 4; ++j) m = fmaxf(m, acc[i][j]);

    // Wave (64-lane) max reduce, then cross-wave via LDS
#pragma unroll
    for (int off = 32; off > 0; off >>= 1) m = fmaxf(m, __shfl_down(m, off, 64));
    if ((t & 63) == 0) red[t >> 6] = m;
    __syncthreads();
    if (t == 0) {
        float M = fmaxf(fmaxf(red[0], red[1]), fmaxf(red[2], red[3]));
        top1[bc] = M * (1.0f / 4096.0f);
    }
}

__global__ __launch_bounds__(256) void mlp_kernel(const float* __restrict__ top1,
                                                  const float* __restrict__ w1,
                                                  const float* __restrict__ w2,
                                                  float* __restrict__ weights) {
    __shared__ float s_top[16 * 256];
    __shared__ float s_w1[256 * 16];
    __shared__ float s_h[16 * 16];
    const int t = threadIdx.x;
#pragma unroll
    for (int i = 0; i < 16; ++i) {
        s_top[i * 256 + t] = top1[i * 256 + t];
        s_w1[i * 256 + t] = w1[i * 256 + t];
    }
    __syncthreads();

    const int b = t >> 4, j = t & 15;
    float s = 0.0f;
    for (int c = 0; c < 256; ++c) s = fmaf(s_top[b * 256 + c], s_w1[c * 16 + j], s);
    s_h[b * 16 + j] = fmaxf(s, 0.0f);
    __syncthreads();

    const int c0 = (t & 15) * 16;
    for (int c = c0; c < c0 + 16; ++c) {
        float s2 = 0.0f;
#pragma unroll
        for (int jj = 0; jj < 16; ++jj) s2 = fmaf(s_h[b * 16 + jj], w2[jj * 256 + c], s2);
        weights[b * 256 + c] = 1.0f / (1.0f + __expf(-s2));
    }
}

__global__ __launch_bounds__(256) void scale_kernel(const float* __restrict__ ip,
                                                    const float* __restrict__ weights,
                                                    float* __restrict__ out) {
    const int i = blockIdx.x * 256 + threadIdx.x;  // float4 index; total 4194304
    const float w = weights[i >> 10];              // 4096 floats per (b,c) / 4 per float4
    float4 v = ((const float4*)ip)[i];
    v.x *= w; v.y *= w; v.z *= w; v.w *= w;
    ((float4*)out)[i] = v;
}

extern "C" void kernel_launch(void* const* d_in, const int* in_sizes, int n_in,
                              void* d_out, int out_size, void* d_ws, size_t ws_size,
                              hipStream_t stream) {
    const float* ip = (const float*)d_in[0];   // [16,256,64,64]
    const float* w1 = (const float*)d_in[1];   // [256,16]
    const float* w2 = (const float*)d_in[2];   // [16,256]
    float* out = (float*)d_out;

    float* top1 = (float*)d_ws;        // 4096 floats
    float* weights = top1 + 4096;      // 4096 floats

    dct_max_kernel<<<4096, 256, 0, stream>>>(ip, top1);
    mlp_kernel<<<1, 256, 0, stream>>>(top1, w1, w2, weights);
    scale_kernel<<<16384, 256, 0, stream>>>(ip, weights, out);
}

// Round 2
// 164.716 us; speedup vs baseline: 1.2594x; 1.2594x over previous
//
#include <hip/hip_runtime.h>
#include <math.h>

// B=16, C=256, H=W=64, r=16.
// dct = (1/4096) * D @ X @ D^T per (b,c) slice, D[u,h] = cos(pi*u*(2h+1)/128)
// We compute Y' = D @ X^T @ D^T = (D @ X @ D^T)^T  -- same max, avoids LDS transpose:
//   stage A: T = D @ X^T   (B-frag B[k][n] = X[n][k] -> X row-major, k contiguous)
//   stage B: Y' = T @ D^T  (B-frag B[k][n] = D[n][k] -> D row-major, k contiguous)
// top1[b,c] = max(slice)/4096; h = relu(top1@w1); weights = sigmoid(h@w2); out = ip*weights

#define S 72  // ushort stride: 144 B rows (16B-aligned for b128, odd 16B-groups for banks)

typedef __attribute__((ext_vector_type(8))) short bf16x8;
typedef __attribute__((ext_vector_type(4))) float f32x4;

__device__ inline unsigned short f2bf(float x) {
    union { float f; unsigned u; } v; v.f = x;
    unsigned r = v.u + 0x7FFF + ((v.u >> 16) & 1);
    return (unsigned short)(r >> 16);
}

__global__ __launch_bounds__(256) void dct_max_kernel(const float* __restrict__ ip,
                                                      float* __restrict__ top1) {
    __shared__ unsigned short Xbf[64 * S];  // X[h][w] bf16 row-major
    __shared__ unsigned short Dbf[64 * S];  // D[u][h] bf16 row-major
    __shared__ unsigned short Tbf[64 * S];  // T[u][w] bf16 row-major
    __shared__ float red[4];

    const int t = threadIdx.x;
    const int bc = blockIdx.x;
    const float4* src4 = (const float4*)(ip + (size_t)bc * 4096);

    // Load X slice (coalesced float4), convert to bf16, store row-major.
#pragma unroll
    for (int i = 0; i < 4; ++i) {
        float4 v = src4[i * 256 + t];
        int h = i * 16 + (t >> 4);
        int w0 = (4 * t) & 63;
        ushort4 p;
        p.x = f2bf(v.x); p.y = f2bf(v.y); p.z = f2bf(v.z); p.w = f2bf(v.w);
        *(ushort4*)&Xbf[h * S + w0] = p;
    }

    // Build D[u][h] = cos(pi * u * (2h+1) / 128) in bf16.
#pragma unroll
    for (int i = 0; i < 16; ++i) {
        int idx = i * 256 + t;
        int u = idx >> 6, h = idx & 63;
        int m = (u * (2 * h + 1)) & 255;
        Dbf[u * S + h] = f2bf(cospif((float)m * (1.0f / 128.0f)));
    }
    __syncthreads();

    const int wv = t >> 6;        // wave 0..3 -> output row-strip [16wv, 16wv+16)
    const int l = t & 63;
    const int m = l & 15;         // row (A) / col (B,C/D)
    const int q = l >> 4;         // quad: k-offset 8q
    const int arow = (16 * wv + m) * S + 8 * q;  // A-frag base (both stages)

    // ---- Stage A: T = D @ X^T ----
    bf16x8 a0 = *(const bf16x8*)&Dbf[arow];
    bf16x8 a1 = *(const bf16x8*)&Dbf[arow + 32];
    f32x4 acc[4];
#pragma unroll
    for (int tn = 0; tn < 4; ++tn) {
        const int brow = (16 * tn + m) * S + 8 * q;
        bf16x8 b0 = *(const bf16x8*)&Xbf[brow];
        bf16x8 b1 = *(const bf16x8*)&Xbf[brow + 32];
        f32x4 c = {0.0f, 0.0f, 0.0f, 0.0f};
        c = __builtin_amdgcn_mfma_f32_16x16x32_bf16(a0, b0, c, 0, 0, 0);
        c = __builtin_amdgcn_mfma_f32_16x16x32_bf16(a1, b1, c, 0, 0, 0);
        acc[tn] = c;
    }
    // C/D layout: col = m (=lane&15) + 16tn, row = 4q + reg + 16wv  (rows owned by this wave)
#pragma unroll
    for (int tn = 0; tn < 4; ++tn)
#pragma unroll
        for (int reg = 0; reg < 4; ++reg)
            Tbf[(16 * wv + 4 * q + reg) * S + 16 * tn + m] = f2bf(acc[tn][reg]);
    __syncthreads();

    // ---- Stage B: Y' = T @ D^T, fused max ----
    a0 = *(const bf16x8*)&Tbf[arow];
    a1 = *(const bf16x8*)&Tbf[arow + 32];
    float mx = -3.4e38f;
#pragma unroll
    for (int tn = 0; tn < 4; ++tn) {
        const int brow = (16 * tn + m) * S + 8 * q;
        bf16x8 b0 = *(const bf16x8*)&Dbf[brow];
        bf16x8 b1 = *(const bf16x8*)&Dbf[brow + 32];
        f32x4 c = {0.0f, 0.0f, 0.0f, 0.0f};
        c = __builtin_amdgcn_mfma_f32_16x16x32_bf16(a0, b0, c, 0, 0, 0);
        c = __builtin_amdgcn_mfma_f32_16x16x32_bf16(a1, b1, c, 0, 0, 0);
        mx = fmaxf(mx, fmaxf(fmaxf(c[0], c[1]), fmaxf(c[2], c[3])));
    }

    // Wave (64-lane) max reduce, then cross-wave via LDS.
#pragma unroll
    for (int off = 32; off > 0; off >>= 1) mx = fmaxf(mx, __shfl_down(mx, off, 64));
    if (l == 0) red[wv] = mx;
    __syncthreads();
    if (t == 0) {
        float M = fmaxf(fmaxf(red[0], red[1]), fmaxf(red[2], red[3]));
        top1[bc] = M * (1.0f / 4096.0f);
    }
}

__global__ __launch_bounds__(256) void mlp_kernel(const float* __restrict__ top1,
                                                  const float* __restrict__ w1,
                                                  const float* __restrict__ w2,
                                                  float* __restrict__ weights) {
    __shared__ float s_top[16 * 256];
    __shared__ float s_w1[256 * 16];
    __shared__ float s_h[16 * 16];
    const int t = threadIdx.x;
#pragma unroll
    for (int i = 0; i < 16; ++i) {
        s_top[i * 256 + t] = top1[i * 256 + t];
        s_w1[i * 256 + t] = w1[i * 256 + t];
    }
    __syncthreads();

    const int b = t >> 4, j = t & 15;
    float s = 0.0f;
    for (int c = 0; c < 256; ++c) s = fmaf(s_top[b * 256 + c], s_w1[c * 16 + j], s);
    s_h[b * 16 + j] = fmaxf(s, 0.0f);
    __syncthreads();

    const int c0 = (t & 15) * 16;
    for (int c = c0; c < c0 + 16; ++c) {
        float s2 = 0.0f;
#pragma unroll
        for (int jj = 0; jj < 16; ++jj) s2 = fmaf(s_h[b * 16 + jj], w2[jj * 256 + c], s2);
        weights[b * 256 + c] = 1.0f / (1.0f + __expf(-s2));
    }
}

__global__ __launch_bounds__(256) void scale_kernel(const float* __restrict__ ip,
                                                    const float* __restrict__ weights,
                                                    float* __restrict__ out) {
    const int i = blockIdx.x * 256 + threadIdx.x;  // float4 index; total 4194304
    const float w = weights[i >> 10];              // 1024 float4 per (b,c)
    float4 v = ((const float4*)ip)[i];
    v.x *= w; v.y *= w; v.z *= w; v.w *= w;
    ((float4*)out)[i] = v;
}

extern "C" void kernel_launch(void* const* d_in, const int* in_sizes, int n_in,
                              void* d_out, int out_size, void* d_ws, size_t ws_size,
                              hipStream_t stream) {
    const float* ip = (const float*)d_in[0];   // [16,256,64,64]
    const float* w1 = (const float*)d_in[1];   // [256,16]
    const float* w2 = (const float*)d_in[2];   // [16,256]
    float* out = (float*)d_out;

    float* top1 = (float*)d_ws;        // 4096 floats
    float* weights = top1 + 4096;      // 4096 floats

    dct_max_kernel<<<4096, 256, 0, stream>>>(ip, top1);
    mlp_kernel<<<1, 256, 0, stream>>>(top1, w1, w2, weights);
    scale_kernel<<<16384, 256, 0, stream>>>(ip, weights, out);
}

// Round 3
// 144.452 us; speedup vs baseline: 1.4361x; 1.1403x over previous
//
#include <hip/hip_runtime.h>
#include <math.h>

// B=16, C=256, H=W=64, r=16.
// dct = (1/4096) * D @ X @ D^T per (b,c) slice, D[u,h] = cos(pi*u*(2h+1)/128)
// Compute Y' = D @ X^T @ D^T = (D @ X @ D^T)^T  (same max, no LDS transpose needed):
//   stage A: T = D @ X^T, stage B: Y' = T @ D^T  (both B-operands row-major k-contiguous)
// k1: 1024 blocks x 4 slices each: build D once/block, prefetch next slice during MFMA.
// k2: fused mlp+scale: per-slice block recomputes weight from L2-hot top1/w1/w2, scales ip.

#define S 72  // ushort stride: 144 B rows (16B-aligned b128, bank-spread)

typedef __attribute__((ext_vector_type(8))) short bf16x8;
typedef __attribute__((ext_vector_type(4))) float f32x4;

__device__ inline unsigned short f2bf(float x) {
    union { float f; unsigned u; } v; v.f = x;
    unsigned r = v.u + 0x7FFF + ((v.u >> 16) & 1);
    return (unsigned short)(r >> 16);
}

__global__ __launch_bounds__(256, 4) void dct_max_kernel(const float* __restrict__ ip,
                                                         float* __restrict__ top1) {
    __shared__ unsigned short Dbf[64 * S];  // D[u][h]
    __shared__ unsigned short Xbf[64 * S];  // X[h][w]
    __shared__ unsigned short Tbf[64 * S];  // T[u][w]
    __shared__ float red[4];

    const int t = threadIdx.x;

    // Build D[u][h] = cos(pi*u*(2h+1)/128) once per block (amortized over 4 slices).
#pragma unroll
    for (int i = 0; i < 16; ++i) {
        int idx = i * 256 + t;
        int u = idx >> 6, h = idx & 63;
        int mm = (u * (2 * h + 1)) & 255;
        Dbf[u * S + h] = f2bf(cospif((float)mm * (1.0f / 128.0f)));
    }

    const int wv = t >> 6;   // wave -> 16-row output strip
    const int l = t & 63;
    const int m = l & 15;
    const int q = l >> 4;
    const int arow = (16 * wv + m) * S + 8 * q;
    const int xh = t >> 4;           // X-store row helper: h = 16*i + (t>>4)
    const int xw0 = (4 * t) & 63;

    const int bc0 = blockIdx.x * 4;
    const float4* src4 = (const float4*)(ip + (size_t)bc0 * 4096);

    // Prefetch slice 0.
    float4 xv[4];
#pragma unroll
    for (int i = 0; i < 4; ++i) xv[i] = src4[i * 256 + t];

    __syncthreads();  // D ready
    const bf16x8 da0 = *(const bf16x8*)&Dbf[arow];        // stage-A A-frag (loop-invariant)
    const bf16x8 da1 = *(const bf16x8*)&Dbf[arow + 32];

    for (int s = 0; s < 4; ++s) {
        // Store prefetched X into LDS (bf16).
#pragma unroll
        for (int i = 0; i < 4; ++i) {
            ushort4 p;
            p.x = f2bf(xv[i].x); p.y = f2bf(xv[i].y);
            p.z = f2bf(xv[i].z); p.w = f2bf(xv[i].w);
            *(ushort4*)&Xbf[(16 * i + xh) * S + xw0] = p;
        }
        __syncthreads();  // X visible

        // Prefetch next slice while MFMA stages run.
        if (s < 3) {
            const float4* nsrc = src4 + (size_t)(s + 1) * 1024;
#pragma unroll
            for (int i = 0; i < 4; ++i) xv[i] = nsrc[i * 256 + t];
        }

        // ---- Stage A: T = D @ X^T ----
        f32x4 acc[4];
#pragma unroll
        for (int tn = 0; tn < 4; ++tn) {
            const int brow = (16 * tn + m) * S + 8 * q;
            bf16x8 b0 = *(const bf16x8*)&Xbf[brow];
            bf16x8 b1 = *(const bf16x8*)&Xbf[brow + 32];
            f32x4 c = {0.0f, 0.0f, 0.0f, 0.0f};
            c = __builtin_amdgcn_mfma_f32_16x16x32_bf16(da0, b0, c, 0, 0, 0);
            c = __builtin_amdgcn_mfma_f32_16x16x32_bf16(da1, b1, c, 0, 0, 0);
            acc[tn] = c;
        }
#pragma unroll
        for (int tn = 0; tn < 4; ++tn)
#pragma unroll
            for (int reg = 0; reg < 4; ++reg)
                Tbf[(16 * wv + 4 * q + reg) * S + 16 * tn + m] = f2bf(acc[tn][reg]);
        __syncthreads();  // T visible; X reads done

        // ---- Stage B: Y' = T @ D^T, fused max ----
        bf16x8 ta0 = *(const bf16x8*)&Tbf[arow];
        bf16x8 ta1 = *(const bf16x8*)&Tbf[arow + 32];
        float mx = -3.4e38f;
#pragma unroll
        for (int tn = 0; tn < 4; ++tn) {
            const int brow = (16 * tn + m) * S + 8 * q;
            bf16x8 b0 = *(const bf16x8*)&Dbf[brow];
            bf16x8 b1 = *(const bf16x8*)&Dbf[brow + 32];
            f32x4 c = {0.0f, 0.0f, 0.0f, 0.0f};
            c = __builtin_amdgcn_mfma_f32_16x16x32_bf16(ta0, b0, c, 0, 0, 0);
            c = __builtin_amdgcn_mfma_f32_16x16x32_bf16(ta1, b1, c, 0, 0, 0);
            mx = fmaxf(mx, fmaxf(fmaxf(c[0], c[1]), fmaxf(c[2], c[3])));
        }

#pragma unroll
        for (int off = 32; off > 0; off >>= 1) mx = fmaxf(mx, __shfl_down(mx, off, 64));
        if (l == 0) red[wv] = mx;
        __syncthreads();  // red visible; Xbf/Tbf free for next slice
        if (t == 0) {
            float M = fmaxf(fmaxf(red[0], red[1]), fmaxf(red[2], red[3]));
            top1[bc0 + s] = M * (1.0f / 4096.0f);
        }
    }
}

// Fused MLP + scale: one block per (b,c) slice. Recomputes h=relu(top1[b,:]@w1)
// (4096 FMA from L2-hot data) then weight=sigmoid(h@w2[:,c]) and scales the slice.
__global__ __launch_bounds__(256) void scale_kernel(const float* __restrict__ ip,
                                                    const float* __restrict__ top1,
                                                    const float* __restrict__ w1,
                                                    const float* __restrict__ w2,
                                                    float* __restrict__ out) {
    __shared__ float h_s[16];
    __shared__ float w_s;
    const int t = threadIdx.x;
    const int bc = blockIdx.x;
    const int b = bc >> 8, c = bc & 255;

    // h[j] = relu(sum_c top1[b,c]*w1[c,j]) : 16 groups of 16 lanes.
    const int j = t >> 4, i = t & 15;
    float partial = 0.0f;
#pragma unroll
    for (int k = 0; k < 16; ++k) {
        int cc = i + 16 * k;
        partial = fmaf(top1[b * 256 + cc], w1[cc * 16 + j], partial);
    }
#pragma unroll
    for (int off = 8; off > 0; off >>= 1) partial += __shfl_xor(partial, off, 16);
    if (i == 0) h_s[j] = fmaxf(partial, 0.0f);
    __syncthreads();

    if (t < 16) {
        float p2 = h_s[t] * w2[t * 256 + c];
#pragma unroll
        for (int off = 8; off > 0; off >>= 1) p2 += __shfl_xor(p2, off, 16);
        if (t == 0) w_s = 1.0f / (1.0f + __expf(-p2));
    }
    __syncthreads();
    const float wt = w_s;

    const float4* ip4 = (const float4*)ip + (size_t)bc * 1024;
    float4* out4 = (float4*)out + (size_t)bc * 1024;
#pragma unroll
    for (int k = 0; k < 4; ++k) {
        float4 v = ip4[k * 256 + t];
        v.x *= wt; v.y *= wt; v.z *= wt; v.w *= wt;
        out4[k * 256 + t] = v;
    }
}

extern "C" void kernel_launch(void* const* d_in, const int* in_sizes, int n_in,
                              void* d_out, int out_size, void* d_ws, size_t ws_size,
                              hipStream_t stream) {
    const float* ip = (const float*)d_in[0];   // [16,256,64,64]
    const float* w1 = (const float*)d_in[1];   // [256,16]
    const float* w2 = (const float*)d_in[2];   // [16,256]
    float* out = (float*)d_out;
    float* top1 = (float*)d_ws;                // 4096 floats

    dct_max_kernel<<<1024, 256, 0, stream>>>(ip, top1);
    scale_kernel<<<4096, 256, 0, stream>>>(ip, top1, w1, w2, out);
}

// Round 6
// 127.063 us; speedup vs baseline: 1.6326x; 1.1369x over previous
//
#include <hip/hip_runtime.h>
#include <math.h>

// B=16, C=256, H=W=64, r=16.
// dct = (1/4096) * D @ X @ D^T per (b,c) slice, D[u,h] = cos(pi*u*(2h+1)/128)
// Y' = D @ X^T @ D^T = (D @ X @ D^T)^T  -- same max, no LDS transpose.
// k1: 1024 blocks x 4 slices: MFMA DCT + fused max -> top1[4096]
// k2: 1024 blocks x 4 slices: bulk ip loads issued first, tiny MLP computed
//     under their shadow, scale + nontemporal store (no RFO traffic).

#define S 72  // ushort stride: 144 B rows (16B-aligned b128, bank-spread)

typedef __attribute__((ext_vector_type(8))) short bf16x8;
typedef __attribute__((ext_vector_type(4))) float f32x4;

__device__ inline unsigned short f2bf(float x) {
    union { float f; unsigned u; } v; v.f = x;
    unsigned r = v.u + 0x7FFF + ((v.u >> 16) & 1);
    return (unsigned short)(r >> 16);
}

__global__ __launch_bounds__(256, 4) void dct_max_kernel(const float* __restrict__ ip,
                                                         float* __restrict__ top1) {
    __shared__ unsigned short Dbf[64 * S];  // D[u][h]
    __shared__ unsigned short Xbf[64 * S];  // X[h][w]
    __shared__ unsigned short Tbf[64 * S];  // T[u][w]
    __shared__ float red[4];

    const int t = threadIdx.x;

#pragma unroll
    for (int i = 0; i < 16; ++i) {
        int idx = i * 256 + t;
        int u = idx >> 6, h = idx & 63;
        int mm = (u * (2 * h + 1)) & 255;
        Dbf[u * S + h] = f2bf(cospif((float)mm * (1.0f / 128.0f)));
    }

    const int wv = t >> 6;
    const int l = t & 63;
    const int m = l & 15;
    const int q = l >> 4;
    const int arow = (16 * wv + m) * S + 8 * q;
    const int xh = t >> 4;
    const int xw0 = (4 * t) & 63;

    const int bc0 = blockIdx.x * 4;
    const float4* src4 = (const float4*)(ip + (size_t)bc0 * 4096);

    float4 xv[4];
#pragma unroll
    for (int i = 0; i < 4; ++i) xv[i] = src4[i * 256 + t];

    __syncthreads();  // D ready
    const bf16x8 da0 = *(const bf16x8*)&Dbf[arow];
    const bf16x8 da1 = *(const bf16x8*)&Dbf[arow + 32];

    for (int s = 0; s < 4; ++s) {
#pragma unroll
        for (int i = 0; i < 4; ++i) {
            ushort4 p;
            p.x = f2bf(xv[i].x); p.y = f2bf(xv[i].y);
            p.z = f2bf(xv[i].z); p.w = f2bf(xv[i].w);
            *(ushort4*)&Xbf[(16 * i + xh) * S + xw0] = p;
        }
        __syncthreads();  // X visible

        if (s < 3) {
            const float4* nsrc = src4 + (size_t)(s + 1) * 1024;
#pragma unroll
            for (int i = 0; i < 4; ++i) xv[i] = nsrc[i * 256 + t];
        }

        // Stage A: T = D @ X^T
        f32x4 acc[4];
#pragma unroll
        for (int tn = 0; tn < 4; ++tn) {
            const int brow = (16 * tn + m) * S + 8 * q;
            bf16x8 b0 = *(const bf16x8*)&Xbf[brow];
            bf16x8 b1 = *(const bf16x8*)&Xbf[brow + 32];
            f32x4 c = {0.0f, 0.0f, 0.0f, 0.0f};
            c = __builtin_amdgcn_mfma_f32_16x16x32_bf16(da0, b0, c, 0, 0, 0);
            c = __builtin_amdgcn_mfma_f32_16x16x32_bf16(da1, b1, c, 0, 0, 0);
            acc[tn] = c;
        }
#pragma unroll
        for (int tn = 0; tn < 4; ++tn)
#pragma unroll
            for (int reg = 0; reg < 4; ++reg)
                Tbf[(16 * wv + 4 * q + reg) * S + 16 * tn + m] = f2bf(acc[tn][reg]);
        __syncthreads();  // T visible

        // Stage B: Y' = T @ D^T, fused max
        bf16x8 ta0 = *(const bf16x8*)&Tbf[arow];
        bf16x8 ta1 = *(const bf16x8*)&Tbf[arow + 32];
        float mx = -3.4e38f;
#pragma unroll
        for (int tn = 0; tn < 4; ++tn) {
            const int brow = (16 * tn + m) * S + 8 * q;
            bf16x8 b0 = *(const bf16x8*)&Dbf[brow];
            bf16x8 b1 = *(const bf16x8*)&Dbf[brow + 32];
            f32x4 c = {0.0f, 0.0f, 0.0f, 0.0f};
            c = __builtin_amdgcn_mfma_f32_16x16x32_bf16(ta0, b0, c, 0, 0, 0);
            c = __builtin_amdgcn_mfma_f32_16x16x32_bf16(ta1, b1, c, 0, 0, 0);
            mx = fmaxf(mx, fmaxf(fmaxf(c[0], c[1]), fmaxf(c[2], c[3])));
        }

#pragma unroll
        for (int off = 32; off > 0; off >>= 1) mx = fmaxf(mx, __shfl_down(mx, off, 64));
        if (l == 0) red[wv] = mx;
        __syncthreads();
        if (t == 0) {
            float M = fmaxf(fmaxf(red[0], red[1]), fmaxf(red[2], red[3]));
            top1[bc0 + s] = M * (1.0f / 4096.0f);
        }
    }
}

// 4 slices per block (same batch b). Bulk loads issued first; MLP computed in
// their shadow; nontemporal stores avoid write-allocate/RFO.
__global__ __launch_bounds__(256, 4) void scale_kernel(const float* __restrict__ ip,
                                                       const float* __restrict__ top1,
                                                       const float* __restrict__ w1,
                                                       const float* __restrict__ w2,
                                                       float* __restrict__ out) {
    __shared__ float h_s[16];
    __shared__ float w_s[4];
    const int t = threadIdx.x;
    const int bc0 = blockIdx.x * 4;
    const int b = bc0 >> 8, c0 = bc0 & 255;

    const f32x4* ip4 = (const f32x4*)ip + (size_t)bc0 * 1024;
    f32x4* out4 = (f32x4*)out + (size_t)bc0 * 1024;

    // ---- Issue MLP's small loads, then the 16 bulk loads (all independent) ----
    const int j = t >> 4, i = t & 15;
    float tvals[16], wvals[16];
#pragma unroll
    for (int k = 0; k < 16; ++k) {
        int cc = i + 16 * k;
        tvals[k] = top1[b * 256 + cc];
        wvals[k] = w1[cc * 16 + j];
    }
    f32x4 v[16];
#pragma unroll
    for (int s = 0; s < 4; ++s)
#pragma unroll
        for (int k = 0; k < 4; ++k) v[s * 4 + k] = ip4[(size_t)s * 1024 + k * 256 + t];

    // ---- MLP under the bulk loads' shadow ----
    float partial = 0.0f;
#pragma unroll
    for (int k = 0; k < 16; ++k) partial = fmaf(tvals[k], wvals[k], partial);
#pragma unroll
    for (int off = 8; off > 0; off >>= 1) partial += __shfl_xor(partial, off, 16);
    if (i == 0) h_s[j] = fmaxf(partial, 0.0f);
    __syncthreads();

    if (t < 64) {  // 4 channels x 16 lanes
        const int sc = t >> 4, jj = t & 15;
        float p2 = h_s[jj] * w2[jj * 256 + (c0 + sc)];
#pragma unroll
        for (int off = 8; off > 0; off >>= 1) p2 += __shfl_xor(p2, off, 16);
        if (jj == 0) w_s[sc] = 1.0f / (1.0f + __expf(-p2));
    }
    __syncthreads();

    // ---- Scale + nontemporal store ----
#pragma unroll
    for (int s = 0; s < 4; ++s) {
        const float wt = w_s[s];
#pragma unroll
        for (int k = 0; k < 4; ++k) {
            f32x4 r = v[s * 4 + k] * wt;
            __builtin_nontemporal_store(r, &out4[(size_t)s * 1024 + k * 256 + t]);
        }
    }
}

extern "C" void kernel_launch(void* const* d_in, const int* in_sizes, int n_in,
                              void* d_out, int out_size, void* d_ws, size_t ws_size,
                              hipStream_t stream) {
    const float* ip = (const float*)d_in[0];   // [16,256,64,64]
    const float* w1 = (const float*)d_in[1];   // [256,16]
    const float* w2 = (const float*)d_in[2];   // [16,256]
    float* out = (float*)d_out;
    float* top1 = (float*)d_ws;                // 4096 floats

    dct_max_kernel<<<1024, 256, 0, stream>>>(ip, top1);
    scale_kernel<<<1024, 256, 0, stream>>>(ip, top1, w1, w2, out);
}